// Round 17
// baseline (89.212 us; speedup 1.0000x reference)
//
#include <hip/hip_runtime.h>

// VQ-VAE vector quantizer: B=32,C=64,H=64,W=64, K=512, DECAY=0.99, EPS=1e-5
// N = 131072 vectors, dim 64.
// R17 = R16 with the argmin selection-chain fix: top-2 tracking was one serial
// (b1,b2) chain through all 256 scores/lane (~3 dep-ops x 4cyc x 256 = 3000
// serial cycles; VALUBusy 51% = latency-bound). Now 4 independent chains (one
// per acc row-group e>>2, disjoint ascending kq sets) merged by the proven
// value-then-index MERGE logic -> bit-identical bkg, 4x selection ILP.
// Everything else frozen at R16.

typedef __attribute__((ext_vector_type(8))) short bf16x8;
typedef __attribute__((ext_vector_type(16))) float f32x16;

#define MFMA32 __builtin_amdgcn_mfma_f32_32x32x16_bf16

__device__ __forceinline__ unsigned short f2bf(float f) {
    unsigned u = __float_as_uint(f);
    return (unsigned short)((u + 0x7fffu + ((u >> 16) & 1u)) >> 16);
}
__device__ __forceinline__ float bf2f(unsigned short h) {
    return __uint_as_float(((unsigned)h) << 16);
}

// ---- prep (R9-proven): esq + split hi/lo fragment-major bf16 codebook ----
__global__ void __launch_bounds__(512)
vq_prep(const float* __restrict__ cb, float* __restrict__ esq, char* __restrict__ cbF) {
    __shared__ float tile[64 * 65];
    const int tid = threadIdx.x;
    const int k0  = blockIdx.x * 64;
    #pragma unroll
    for (int i = tid; i < 4096; i += 512)
        tile[(i >> 6) * 65 + (i & 63)] = cb[k0 * 64 + i];
    __syncthreads();
    const int u  = tid >> 6;
    const int kl = tid & 63;
    const float* row = tile + kl * 65;
    const int cbase = (u >> 1) * 16 + (u & 1) * 8;
    bf16x8 h8, l8;
    #pragma unroll
    for (int j = 0; j < 8; ++j) {
        float e = row[cbase + j];
        unsigned short hb = f2bf(e);
        float lo = e - bf2f(hb);
        h8[j] = (short)hb;
        l8[j] = (short)f2bf(lo);
    }
    const size_t idx = (size_t)(u * 512 + k0 + kl) * 16;
    *(bf16x8*)(cbF + idx)         = h8;
    *(bf16x8*)(cbF + 65536 + idx) = l8;
    if (u == 0) {
        float s = 0.f;
        #pragma unroll
        for (int c = 0; c < 64; ++c) { float v = row[c]; s = fmaf(v, v, s); }
        esq[k0 + kl] = s;
    }
}

// top-2 update; kq ascending -> strict < keeps first (numpy argmin semantics)
__device__ __forceinline__ void upd(float s, int kq, float& b1, int& q1, float& b2, int& q2) {
    bool t1 = s < b1;
    bool t2 = s < b2;
    float nb2 = t1 ? b1 : (t2 ? s : b2);
    int   nq2 = t1 ? q1 : (t2 ? kq : q2);
    b2 = nb2; q2 = nq2;
    b1 = t1 ? s : b1;
    q1 = t1 ? kq : q1;
}

// merge top-2 tuple B into A (disjoint kq sets; value-then-index first-min,
// mirrors the proven hh-MERGE logic without shuffles)
__device__ __forceinline__ void merge2(float& b1, int& q1, float& b2, int& q2,
                                       float ob1, int ok1, float ob2, int ok2) {
    bool t = (ob1 < b1) || (ob1 == b1 && ok1 < q1);
    float w1  = t ? ob1 : b1;   int wk1  = t ? ok1 : q1;
    float l1  = t ? b1  : ob1;  int lk1  = t ? q1  : ok1;   // loser of firsts
    float w2c = t ? ob2 : b2;   int wk2c = t ? ok2 : q2;    // winner's second
    bool t2 = (w2c < l1) || (w2c == l1 && wk2c < lk1);
    b1 = w1; q1 = wk1;
    b2 = t2 ? w2c : l1;
    q2 = t2 ? wk2c : lk1;
}

// exact fp32 re-decision between k1,k2 (R2/R9-proven ordering)
__device__ __forceinline__ int refine_pair(int k1, int k2, long gx,
        const float* __restrict__ x, const float* __restrict__ cbg,
        const float* esq) {
    const float4* e1 = (const float4*)(cbg + (k1 << 6));
    const float4* e2 = (const float4*)(cbg + (k2 << 6));
    float a0 = 0.f, a1 = 0.f, c0 = 0.f, c1 = 0.f;
    #pragma unroll 4
    for (int j = 0; j < 16; ++j) {
        float4 ea = e1[j], eb = e2[j];
        float x0 = x[gx + (long)(4 * j + 0) * 4096];
        float x1 = x[gx + (long)(4 * j + 1) * 4096];
        float x2 = x[gx + (long)(4 * j + 2) * 4096];
        float x3 = x[gx + (long)(4 * j + 3) * 4096];
        a0 = fmaf(x0, ea.x, a0); a1 = fmaf(x1, ea.y, a1);
        a0 = fmaf(x2, ea.z, a0); a1 = fmaf(x3, ea.w, a1);
        c0 = fmaf(x0, eb.x, c0); c1 = fmaf(x1, eb.y, c1);
        c0 = fmaf(x2, eb.z, c0); c1 = fmaf(x3, eb.w, c1);
    }
    float s1 = esq[k1] - 2.f * (a0 + a1);
    float s2 = esq[k2] - 2.f * (c0 + c1);
    return (s2 < s1 || (s2 == s1 && k2 < k1)) ? k2 : k1;
}

// LDS: cbhi 16384 fl (64KB) | esq 512 fl = 67,584 B -> 2 blocks/CU, 4 waves/SIMD
#define AM_LDS_FLOATS 16896

__global__ void __launch_bounds__(512, 2)
vq_argmin(const float* __restrict__ x, const float* __restrict__ cbg,
          const float* __restrict__ esqg, const char* __restrict__ cbF,
          unsigned short* __restrict__ bkg, float* __restrict__ zero528) {
    extern __shared__ float lds[];
    float* esq = lds + 16384;
    const bf16x8* chi   = (const bf16x8*)lds;
    const bf16x8* clo_g = (const bf16x8*)(cbF + 65536);   // lo stays in L2 (64KB hot)
    const int tid  = threadIdx.x;
    const int lane = tid & 63;
    const int wv   = tid >> 6;     // 0..7
    const int l31  = lane & 31;
    const int hh   = lane >> 5;

    // ---- stage hi-codebook (coalesced float4 copy) + esq ----
    {
        const float4* src = (const float4*)cbF;
        float4* dst = (float4*)lds;
        #pragma unroll
        for (int i = tid; i < 4096; i += 512) dst[i] = src[i];
        esq[tid] = esqg[tid];
    }
    // zero hsum(512)+acc_loss(16): all blocks write 0 -- race-safe
    zero528[tid] = 0.f;
    if (tid < 16) zero528[512 + tid] = 0.f;

    // ---- B build: 1 n-tile per wave (-2x, hi/lo via cvt_pk; R9-proven) ----
    const int nb = blockIdx.x * 256 + wv * 32;    // this wave's 32 n
    bf16x8 Bh[4], Bl[4];
    {
        const int n = nb + l31;
        const long gx = (long)(n >> 12) * 262144 + (long)((n >> 6) & 63) * 64 + (n & 63);
        #pragma unroll
        for (int cs = 0; cs < 4; ++cs) {
            float v[8];
            #pragma unroll
            for (int j = 0; j < 8; ++j)
                v[j] = -2.f * x[gx + (long)(cs * 16 + hh * 8 + j) * 4096];
            union { unsigned u[4]; bf16x8 v8; } uh, ul;
            #pragma unroll
            for (int p = 0; p < 4; ++p) {
                unsigned hp, lp;
                asm("v_cvt_pk_bf16_f32 %0, %1, %2" : "=v"(hp) : "v"(v[2*p]), "v"(v[2*p+1]));
                float r0 = v[2*p]     - __uint_as_float(hp << 16);
                float r1 = v[2*p + 1] - __uint_as_float(hp & 0xFFFF0000u);
                asm("v_cvt_pk_bf16_f32 %0, %1, %2" : "=v"(lp) : "v"(r0), "v"(r1));
                uh.u[p] = hp; ul.u[p] = lp;
            }
            Bh[cs] = uh.v8; Bl[cs] = ul.v8;
        }
    }
    __syncthreads();

    // ---- K loop: 16 tiles x 32 codes; Ah from LDS, Al from L2 (ping-pong);
    //      selection split into 4 independent chains (g = e>>2) ----
    float b1[4] = {3.4e38f, 3.4e38f, 3.4e38f, 3.4e38f};
    float b2[4] = {3.4e38f, 3.4e38f, 3.4e38f, 3.4e38f};
    int   q1[4] = {0, 0, 0, 0};
    int   q2[4] = {0, 0, 0, 0};
    bf16x8 Xl[4], Yl[4];

#define LOADAL(Al, kt) { _Pragma("unroll") for (int cs = 0; cs < 4; ++cs) { \
        Al[cs] = clo_g[(cs * 2 + hh) * 512 + (kt) * 32 + l31]; } }

#define STEP(Al, kt) { \
        bf16x8 Ah[4]; \
        _Pragma("unroll") for (int cs = 0; cs < 4; ++cs) \
            Ah[cs] = chi[(cs * 2 + hh) * 512 + (kt) * 32 + l31]; \
        f32x16 acc; \
        _Pragma("unroll") for (int g = 0; g < 4; ++g) { \
            float4 e4 = *(const float4*)(esq + (kt) * 32 + 8 * g + 4 * hh); \
            acc[4*g] = e4.x; acc[4*g+1] = e4.y; acc[4*g+2] = e4.z; acc[4*g+3] = e4.w; } \
        _Pragma("unroll") for (int cs = 0; cs < 4; ++cs) { \
            acc = MFMA32(Ah[cs], Bh[cs], acc, 0, 0, 0); \
            acc = MFMA32(Al[cs], Bh[cs], acc, 0, 0, 0); \
            acc = MFMA32(Ah[cs], Bl[cs], acc, 0, 0, 0); } \
        _Pragma("unroll") for (int e = 0; e < 16; ++e) { \
            const int g = e >> 2; \
            int kq = (kt) * 32 + (e & 3) + 8 * g; \
            upd(acc[e], kq, b1[g], q1[g], b2[g], q2[g]); } }

    LOADAL(Xl, 0)
    #pragma unroll 1
    for (int ktp = 0; ktp < 16; ktp += 2) {
        LOADAL(Yl, ktp + 1)
        STEP(Xl, ktp)
        if (ktp + 2 < 16) LOADAL(Xl, ktp + 2)
        STEP(Yl, ktp + 1)
    }

    // ---- merge the 4 chains (disjoint kq sets; proven merge logic) ----
    merge2(b1[0], q1[0], b2[0], q2[0], b1[1], q1[1], b2[1], q2[1]);
    merge2(b1[2], q1[2], b2[2], q2[2], b1[3], q1[3], b2[3], q2[3]);
    merge2(b1[0], q1[0], b2[0], q2[0], b1[2], q1[2], b2[2], q2[2]);

    // ---- merge hh halves (true k = kq + 4*hh) + in-kernel refine + final bkg ----
    {
        float mb1 = b1[0], mb2 = b2[0];
        int   mk1 = q1[0] + 4 * hh, mk2 = q2[0] + 4 * hh;
        float ob1 = __shfl_xor(mb1, 32, 64); int ok1 = __shfl_xor(mk1, 32, 64);
        float ob2 = __shfl_xor(mb2, 32, 64); int ok2 = __shfl_xor(mk2, 32, 64);
        bool t = (ob1 < mb1) || (ob1 == mb1 && ok1 < mk1);
        float w1 = t ? ob1 : mb1;  int wk1 = t ? ok1 : mk1;
        float l1 = t ? mb1 : ob1;  int lk1 = t ? mk1 : ok1;
        float w2c = t ? ob2 : mb2; int wk2c = t ? ok2 : mk2;
        bool t2 = (w2c < l1) || (w2c == l1 && wk2c < lk1);
        float w2 = t2 ? w2c : l1;  int wk2 = t2 ? wk2c : lk1;
        if (hh == 0) {
            int kk = wk1;
            if (wk2 != wk1 && (w2 - w1 < 2e-3f)) {
                const int n = nb + l31;
                const long gx = (long)(n >> 12) * 262144
                              + (long)((n >> 6) & 63) * 64 + (n & 63);
                kk = refine_pair(wk1, wk2, gx, x, cbg, esq);
            }
            bkg[nb + l31] = (unsigned short)kk;
        }
    }
#undef LOADAL
#undef STEP
}

// ---- fused consumers of bkg: blocks 0-255 out/loss/hist, 256-511 segsum GEMM ----
// dynamic LDS: 33536 ushort = 67,072 B (segsum: xb 64*516 + kb 512; out: 520 fl)
#define FUSED_LDS_BYTES (33536 * 2)

__global__ void __launch_bounds__(512)
vq_fused(const float* __restrict__ x, const float* __restrict__ cbg,
         const unsigned short* __restrict__ bkg, float* __restrict__ out,
         float* __restrict__ hsum, float* __restrict__ acc_loss,
         float* __restrict__ slabs) {
    extern __shared__ unsigned short sm16[];
    const int tid = threadIdx.x;
    if (blockIdx.x < 256) {
        // ---- out (= q, == x+(q-x) to 1 ulp, R5-proven) + loss + counts ----
        float* hist = (float*)sm16;          // 512 floats
        float* lred = (float*)sm16 + 512;    // 8 floats
        hist[tid] = 0.f;
        __syncthreads();
        const int n  = blockIdx.x * 512 + tid;
        const long gx = (long)(n >> 12) * 262144 + (long)((n >> 6) & 63) * 64 + (n & 63);
        const int k1 = bkg[n];
        atomicAdd(&hist[k1], 1.0f);
        const float4* q4 = (const float4*)(cbg + (k1 << 6));
        float lsum = 0.f;
        #pragma unroll
        for (int j = 0; j < 16; ++j) {
            float4 q = q4[j];
            const float qv[4] = {q.x, q.y, q.z, q.w};
            #pragma unroll
            for (int r = 0; r < 4; ++r) {
                const int c = 4 * j + r;
                float xc = x[gx + (long)c * 4096];
                out[gx + (long)c * 4096] = qv[r];
                float d = xc - qv[r];
                lsum = fmaf(d, d, lsum);
            }
        }
        #pragma unroll
        for (int o = 32; o > 0; o >>= 1) lsum += __shfl_down(lsum, o, 64);
        if ((tid & 63) == 0) lred[tid >> 6] = lsum;
        __syncthreads();
        if (tid == 0) {
            float l = ((lred[0] + lred[1]) + (lred[2] + lred[3]))
                    + ((lred[4] + lred[5]) + (lred[6] + lred[7]));
            atomicAdd(acc_loss, l);
        }
        { float v = hist[tid]; if (v != 0.f) atomicAdd(&hsum[tid], v); }
    } else {
        // ---- segment sum as onehot MFMA GEMM, LDS-staged x-tile (R9 math) ----
        unsigned short* xb = sm16;           // [64][516] bf16, 516-pad
        unsigned short* kb = sm16 + 33024;   // 512 indices
        const int lane = tid & 63;
        const int w    = tid >> 6;
        const int l31  = lane & 31;
        const int hh   = lane >> 5;
        const int bix  = blockIdx.x - 256;
        const int n0   = bix * 512;
        const float* xpl = x + (long)(n0 >> 12) * 262144 + (n0 & 4095);

        kb[tid] = bkg[n0 + tid];
        #pragma unroll
        for (int i = 0; i < 16; ++i) {
            const int f  = tid + i * 512;        // 0..8191 float4s
            const int c  = f >> 7;
            const int n4 = (f & 127) << 2;
            float4 v = *(const float4*)(xpl + (long)c * 4096 + n4);
            ushort4 o;
            o.x = f2bf(v.x); o.y = f2bf(v.y); o.z = f2bf(v.z); o.w = f2bf(v.w);
            *(ushort4*)(xb + c * 516 + n4) = o;
        }
        __syncthreads();

        const int t0 = w * 32 + l31;
        const int t1 = (w + 8) * 32 + l31;
        f32x16 aA0 = {}, aA1 = {}, aB0 = {}, aB1 = {};

        #pragma unroll 1
        for (int b16 = 0; b16 < 32; ++b16) {
            const int nofs = b16 * 16 + hh * 8;
            ushort4 p0a = *(const ushort4*)(xb + l31 * 516 + nofs);
            ushort4 p0b = *(const ushort4*)(xb + l31 * 516 + nofs + 4);
            ushort4 p1a = *(const ushort4*)(xb + (32 + l31) * 516 + nofs);
            ushort4 p1b = *(const ushort4*)(xb + (32 + l31) * 516 + nofs + 4);
            bf16x8 Bf0, Bf1;
            Bf0[0] = (short)p0a.x; Bf0[1] = (short)p0a.y;
            Bf0[2] = (short)p0a.z; Bf0[3] = (short)p0a.w;
            Bf0[4] = (short)p0b.x; Bf0[5] = (short)p0b.y;
            Bf0[6] = (short)p0b.z; Bf0[7] = (short)p0b.w;
            Bf1[0] = (short)p1a.x; Bf1[1] = (short)p1a.y;
            Bf1[2] = (short)p1a.z; Bf1[3] = (short)p1a.w;
            Bf1[4] = (short)p1b.x; Bf1[5] = (short)p1b.y;
            Bf1[6] = (short)p1b.z; Bf1[7] = (short)p1b.w;
            ushort4 k4a = *(const ushort4*)(kb + nofs);
            ushort4 k4b = *(const ushort4*)(kb + nofs + 4);
            const int kk[8] = {k4a.x, k4a.y, k4a.z, k4a.w,
                               k4b.x, k4b.y, k4b.z, k4b.w};
            bf16x8 A0, A1;
            #pragma unroll
            for (int j = 0; j < 8; ++j) {
                A0[j] = (kk[j] == t0) ? (short)0x3F80 : (short)0;
                A1[j] = (kk[j] == t1) ? (short)0x3F80 : (short)0;
            }
            aA0 = MFMA32(A0, Bf0, aA0, 0, 0, 0);
            aA1 = MFMA32(A0, Bf1, aA1, 0, 0, 0);
            aB0 = MFMA32(A1, Bf0, aB0, 0, 0, 0);
            aB1 = MFMA32(A1, Bf1, aB1, 0, 0, 0);
        }
        float* slab = slabs + (long)bix * 32768;
        #pragma unroll
        for (int e = 0; e < 16; ++e) {
            const int row = (e & 3) + 8 * (e >> 2) + 4 * hh;
            slab[(w * 32 + row) * 64 + l31]            = aA0[e];
            slab[(w * 32 + row) * 64 + 32 + l31]       = aA1[e];
            slab[((w + 8) * 32 + row) * 64 + l31]      = aB0[e];
            slab[((w + 8) * 32 + row) * 64 + 32 + l31] = aB1[e];
        }
    }
}

// ---- final: scalars (block 0) + codebook; smoothed recomputed per block ----
__global__ void __launch_bounds__(512)
vq_final(const float* __restrict__ slabs, const float* __restrict__ hsum,
         const float* __restrict__ acc_loss, const float* __restrict__ ema_cs,
         const float* __restrict__ ema_w, float* __restrict__ out_scalars,
         float* __restrict__ out_cb) {
    __shared__ float sm[512];
    __shared__ float s_red[17];
    const int tid = threadIdx.x;           // tid == code k
    float cnt = hsum[tid];
    float ncs = 0.99f * ema_cs[tid] + 0.01f * cnt;
    float v1 = ncs;
    float v2 = (cnt > 0.f) ? 1.f : 0.f;
    #pragma unroll
    for (int o = 32; o > 0; o >>= 1) {
        v1 += __shfl_down(v1, o, 64);
        v2 += __shfl_down(v2, o, 64);
    }
    const int wv = tid >> 6;
    if ((tid & 63) == 0) { s_red[wv] = v1; s_red[wv + 8] = v2; }
    __syncthreads();
    if (tid == 0) {
        float nn = 0.f, uq = 0.f;
        #pragma unroll
        for (int i = 0; i < 8; ++i) { nn += s_red[i]; uq += s_red[i + 8]; }
        s_red[16] = nn;
        if (blockIdx.x == 0) {
            out_scalars[0] = acc_loss[0] / 8388608.f;
            out_scalars[1] = uq;
        }
    }
    __syncthreads();
    float nn = s_red[16];
    sm[tid] = (ncs + 1e-5f) / (nn + 512.f * 1e-5f) * nn;
    __syncthreads();
    const int e = blockIdx.x * 512 + tid;  // e = k*64 + c
    float s = 0.f;
    #pragma unroll 8
    for (int b = 0; b < 256; ++b) s += slabs[(long)b * 32768 + e];
    float nw = 0.99f * ema_w[e] + 0.01f * s;
    out_cb[e] = nw / sm[e >> 6];
}

extern "C" void kernel_launch(void* const* d_in, const int* in_sizes, int n_in,
                              void* d_out, int out_size, void* d_ws, size_t ws_size,
                              hipStream_t stream) {
    const float* x      = (const float*)d_in[0];
    const float* cb     = (const float*)d_in[1];
    const float* ema_cs = (const float*)d_in[2];
    const float* ema_w  = (const float*)d_in[3];

    float* out     = (float*)d_out;
    float* scalars = out + 8388608;
    float* out_cb  = out + 8388610;
    float* ws      = (float*)d_ws;

    // ws layout (floats):
    float* slabs    = ws;                               // 256*32768 = 8,388,608 (32MB)
    float* hsum     = slabs + 8388608;                  // 512
    float* acc_loss = hsum + 512;                       // 16
    float* esq      = acc_loss + 16;                    // 512
    char*  cbF      = (char*)(esq + 512);               // 131072 B
    unsigned short* bkg = (unsigned short*)(cbF + 131072);   // 131072 u16
    // total ~34.1 MB (R4 proved >= 34.6 MB available)

    vq_prep<<<8, 512, 0, stream>>>(cb, esq, cbF);
    vq_argmin<<<512, 512, AM_LDS_FLOATS * sizeof(float), stream>>>(x, cb, esq, cbF, bkg, hsum);
    vq_fused<<<512, 512, FUSED_LDS_BYTES, stream>>>(x, cb, bkg, out, hsum, acc_loss, slabs);
    vq_final<<<64, 512, 0, stream>>>(slabs, hsum, acc_loss, ema_cs, ema_w, scalars, out_cb);
}